// Round 11
// baseline (2065.171 us; speedup 1.0000x reference)
//
#include <hip/hip_runtime.h>
#include <hip/hip_bf16.h>
#include <stdint.h>

#define T_STEPS 512
#define BATCH   64
#define DIN     512
#define DLAT    1024
#define NWG     256          // 64 col-tiles x 4 row-blocks

typedef __bf16 bf16_t;
typedef __bf16 bf16x4 __attribute__((ext_vector_type(4)));
typedef __bf16 bf16x8 __attribute__((ext_vector_type(8)));
typedef float  f32x4  __attribute__((ext_vector_type(4)));

// ---- workspace layout (bytes) ----
#define XB_OFF     0u                        // bf16 x [512][64][512] = 33,554,432
#define WXT_OFF    33554432u                 // bf16 x-weights frag-ordered = 4,194,304
#define FLAGS_OFF  (WXT_OFF + 4194304u)      // u32 flags[513][256] = 525,312
#define HS_OFF     (FLAGS_OFF + 525312u)     // bf16 h ring [2][64][1024] = 262,144
#define SLOT_ELEMS 65536
#define MEMSET_BYTES (525312u + 262144u)     // flags + both h slots

// ---- LDS layout (bytes) ----
#define HW_OFF_B   0          // h-weights [64 cols][1024 k] bf16, swizzled = 131,072
#define PART_OFF_B 131072     // f32 [4 waves][64 cols][20 rows-pad] = 20,480
#define LDS_BYTES  152064     // forces 1 WG/CU

__global__ void xconv_kernel(const float* __restrict__ x, bf16_t* __restrict__ xb) {
    size_t i = ((size_t)blockIdx.x * 256 + threadIdx.x) * 4;
    const float4 v = *(const float4*)(x + i);
    bf16x4 o;
    o[0] = (bf16_t)v.x; o[1] = (bf16_t)v.y; o[2] = (bf16_t)v.z; o[3] = (bf16_t)v.w;
    *(bf16x4*)(xb + i) = o;
}

// x-weight prep: wxt frag order. Chunk gid (16B): lane = gid&63, f = gid>>6;
// cf = f&3 (gate), ks = (f>>2)&3, wv = (f>>4)&3, ct = f>>6.
// elem e: W_gate[wv*128+ks*32+(lane>>4)*8+e][ct*16+(lane&15)]
__global__ void wxt_prep(const float* __restrict__ Wf, const float* __restrict__ Wi,
                         const float* __restrict__ Wo, const float* __restrict__ Wu,
                         bf16_t* __restrict__ wxt) {
    const int gid  = blockIdx.x * 256 + threadIdx.x;   // 0..262143
    const int lane = gid & 63;
    const int f    = gid >> 6;
    const int cf   = f & 3;
    const int ks   = (f >> 2) & 3;
    const int wv   = (f >> 4) & 3;
    const int ct   = f >> 6;
    const float* Wg = (cf == 0) ? Wf : (cf == 1) ? Wi : (cf == 2) ? Wo : Wu;
    const int k0 = wv * 128 + ks * 32 + (lane >> 4) * 8;
    const int j  = ct * 16 + (lane & 15);
    bf16x8 v;
#pragma unroll
    for (int e = 0; e < 8; ++e) v[e] = (bf16_t)Wg[(size_t)(k0 + e) * DLAT + j];
    *(bf16x8*)(wxt + (size_t)gid * 8) = v;
}

__device__ __forceinline__ float rcp_(float x) { return __builtin_amdgcn_rcpf(x); }
__device__ __forceinline__ float sigmoidf_(float v) { return rcp_(1.f + __expf(-v)); }
__device__ __forceinline__ float tanh_fast(float x) {
    const float ax = fabsf(x);
    const float e  = __expf(-2.f * ax);
    const float t  = (1.f - e) * rcp_(1.f + e);
    return copysignf(t, x);
}

// h-weight frag from LDS: col c, h-k base kh (lane adds lq*8)
__device__ __forceinline__ bf16x8 ldsHW(const char* lds, int c, int kh, int lq) {
    const uint32_t off = (uint32_t)(c * 2048 + kh * 2 + lq * 16)
                       ^ (uint32_t)((c & 7) << 4);
    return *(const bf16x8*)(lds + HW_OFF_B + off);
}

// sc1 (MALL-coherent) 16B load, issued without wait (h path — proven protocol)
__device__ __forceinline__ bf16x8 ldh16_sc1(const bf16_t* p) {
    f32x4 r;
    asm volatile("global_load_dwordx4 %0, %1, off sc1"
                 : "=v"(r) : "v"(p) : "memory");
    return __builtin_bit_cast(bf16x8, r);
}

// device-scope 2B write-through store (per-thread direct publish)
__device__ __forceinline__ void sth2(bf16_t* p, bf16_t v) {
    const uint32_t d = (uint32_t)__builtin_bit_cast(uint16_t, v);
    asm volatile("global_store_short %0, %1, off sc1"
                 :: "v"(p), "v"(d) : "memory");
}

__device__ __forceinline__ void stflag(uint32_t* p, uint32_t v) {
    asm volatile("global_store_dword %0, %1, off sc1" :: "v"(p), "v"(v) : "memory");
}

__launch_bounds__(256, 1)
__global__ void lstm_main(const float* __restrict__ Wf, const float* __restrict__ Wi,
                          const float* __restrict__ Wo, const float* __restrict__ Wu,
                          const float* __restrict__ bfp, const float* __restrict__ bip,
                          const float* __restrict__ bop, const float* __restrict__ bup,
                          const bf16_t* __restrict__ xb,
                          const bf16_t* __restrict__ wxt,
                          bf16_t* __restrict__ hslots,
                          uint32_t* __restrict__ flags,
                          float* __restrict__ out) {
    extern __shared__ char ldsraw[];
    float* part = (float*)(ldsraw + PART_OFF_B);   // [4][64 cols][20 rows]

    const int tid  = threadIdx.x;
    const int wv   = tid >> 6;       // wave = k-slice
    const int lane = tid & 63;
    const int lm   = lane & 15;
    const int lq   = lane >> 4;
    const int rb   = blockIdx.x & 3;    // row-block: rows [rb*16, +16)
    const int ct   = blockIdx.x >> 2;   // col-tile: j [ct*16, +16), all 4 gates
    const int r0   = rb * 16;
    const int j0   = ct * 16;

    // ---- one-time: h-weights -> LDS [64 cols][1024 k] bf16, swizzled ----
    {
        const int c    = tid & 63;
        const int gate = c >> 4;
        const int jj   = c & 15;
        const float* Wg = (gate == 0) ? Wf : (gate == 1) ? Wi : (gate == 2) ? Wo : Wu;
        const float* src = Wg + (size_t)512 * DLAT + (j0 + jj);
        for (int kb = tid >> 6; kb < 128; kb += 4) {
            const int k0 = kb * 8;
            bf16x8 v;
#pragma unroll
            for (int e = 0; e < 8; ++e) v[e] = (bf16_t)src[(size_t)(k0 + e) * DLAT];
            const uint32_t a = (uint32_t)(c * 2048 + kb * 16) ^ (uint32_t)((c & 7) << 4);
            *(bf16x8*)(ldsraw + HW_OFF_B + a) = v;
        }
    }

    // elementwise ownership: tid = row_l*16 + jj
    const int row_l = tid >> 4;          // 0..15
    const int jj    = tid & 15;          // 0..15
    const float bias_r[4] = { bfp[j0 + jj], bip[j0 + jj], bop[j0 + jj], bup[j0 + jj] };
    float cst = 0.f;

    // per-wave x-weight base (frag-ordered, cached reads — read-only, safe)
    const bf16_t* wx_base = wxt + (size_t)((ct * 4 + wv) * 16) * 512;

    __syncthreads();   // weights visible

    f32x4 acc[4];
#pragma unroll
    for (int cf = 0; cf < 4; ++cf) acc[cf] = (f32x4){0.f, 0.f, 0.f, 0.f};

    // ---- prologue: x_0 GEMM (wave x-k slice [wv*128, +128)) ----
    {
        const bf16_t* xa = xb + (size_t)(r0 + lm) * DIN + wv * 128 + lq * 8;
#pragma unroll
        for (int ks = 0; ks < 4; ++ks) {
            const bf16x8 a = *(const bf16x8*)(xa + ks * 32);
#pragma unroll
            for (int cf = 0; cf < 4; ++cf) {
                const bf16x8 b = *(const bf16x8*)(wx_base + (ks * 4 + cf) * 512 + lane * 8);
                acc[cf] = __builtin_amdgcn_mfma_f32_16x16x32_bf16(a, b, acc[cf], 0, 0, 0);
            }
        }
    }

    for (int t = 0; t < T_STEPS; ++t) {
        const bf16_t* hprev = hslots + (size_t)(t & 1) * SLOT_ELEMS;
        bf16_t*       hnext = hslots + (size_t)((t + 1) & 1) * SLOT_ELEMS;

        // ---- per-wave narrowed poll: wave wv's h k-slice [wv*256,+256) is
        // produced by the 16 WGs ct' in [wv*16,+16) with our rb. Each wave
        // starts as soon as ITS producers land. Publish stays behind bar2
        // (union of all 4 waves' polls = all 64 same-rb WGs = exactly the
        // readers of our region) so 2-slot overwrite stays safe. ----
        if (t > 0) {
            const uint32_t* fp = flags + (size_t)t * 256
                               + (uint32_t)((wv * 16 + lm) * 4 + rb);
            while (true) {
                uint32_t v;
                asm volatile("global_load_dword %0, %1, off sc1\n\ts_waitcnt vmcnt(0)"
                             : "=v"(v) : "v"(fp) : "memory");
                if (__all(v == 1u)) break;
            }
            asm volatile("" ::: "memory");
        } else {
            asm volatile("s_waitcnt vmcnt(0)" ::: "memory");   // clean vmcnt baseline
        }

        // ---- h GEMM: 8 sc1 16B loads (16 rows x 256 k per wave), two-stage
        // vmcnt; B-frags from LDS ----
        {
            const bf16_t* hb = hprev + (size_t)(r0 + lm) * DLAT + wv * 256 + lq * 8;
            bf16x8 ha[8];
#pragma unroll
            for (int ks = 0; ks < 8; ++ks) ha[ks] = ldh16_sc1(hb + ks * 32);
            asm volatile("s_waitcnt vmcnt(4)" ::: "memory");
            __builtin_amdgcn_sched_barrier(0);
#pragma unroll
            for (int ks = 0; ks < 4; ++ks) {
                const int kh = wv * 256 + ks * 32;
#pragma unroll
                for (int cf = 0; cf < 4; ++cf) {
                    const bf16x8 b = ldsHW(ldsraw, cf * 16 + lm, kh, lq);
                    acc[cf] = __builtin_amdgcn_mfma_f32_16x16x32_bf16(ha[ks], b, acc[cf], 0, 0, 0);
                }
            }
            asm volatile("s_waitcnt vmcnt(0)" ::: "memory");
            __builtin_amdgcn_sched_barrier(0);
#pragma unroll
            for (int ks = 4; ks < 8; ++ks) {
                const int kh = wv * 256 + ks * 32;
#pragma unroll
                for (int cf = 0; cf < 4; ++cf) {
                    const bf16x8 b = ldsHW(ldsraw, cf * 16 + lm, kh, lq);
                    acc[cf] = __builtin_amdgcn_mfma_f32_16x16x32_bf16(ha[ks], b, acc[cf], 0, 0, 0);
                }
            }
        }

        // ---- cross-wave K-reduction via LDS ----
        // acc[cf][i] = (row = lq*4+i, col = cf*16+lm)
#pragma unroll
        for (int cf = 0; cf < 4; ++cf)
            *(f32x4*)&part[(wv * 64 + cf * 16 + lm) * 20 + lq * 4] = acc[cf];
        __syncthreads();   // barrier #1

        float gs[4];
#pragma unroll
        for (int g = 0; g < 4; ++g) {
            const int c = g * 16 + jj;
            gs[g] = part[(0 * 64 + c) * 20 + row_l] + part[(1 * 64 + c) * 20 + row_l]
                  + part[(2 * 64 + c) * 20 + row_l] + part[(3 * 64 + c) * 20 + row_l]
                  + bias_r[g];
        }
        const float ft = sigmoidf_(gs[0]);
        const float it = sigmoidf_(gs[1]);
        const float ot = sigmoidf_(gs[2]);
        const float ut = tanh_fast(gs[3]);
        cst = ft * cst + it * ut;
        const float hv = ot * tanh_fast(cst);

        // ---- direct per-thread 2B sc1 publish (before any barrier);
        // 16 lanes/row coalesce into one 32B sector ----
        sth2(hnext + (size_t)(r0 + row_l) * DLAT + j0 + jj, (bf16_t)hv);
        asm volatile("s_waitcnt vmcnt(0)" ::: "memory");   // own store at MALL
        __syncthreads();   // barrier #2: all publishes drained + part reads done
        if (tid == 0)
            stflag(flags + (size_t)(t + 1) * 256 + blockIdx.x, 1u);

        // out store (cached path) after the publish chain
        out[((size_t)t * BATCH + r0 + row_l) * DLAT + j0 + jj] = hv;

        // ---- overlap: x_{t+1} GEMM into fresh acc while others finish ----
#pragma unroll
        for (int cf = 0; cf < 4; ++cf) acc[cf] = (f32x4){0.f, 0.f, 0.f, 0.f};
        if (t + 1 < T_STEPS) {
            const bf16_t* xa = xb + (size_t)(t + 1) * (BATCH * DIN)
                             + (size_t)(r0 + lm) * DIN + wv * 128 + lq * 8;
#pragma unroll
            for (int ks = 0; ks < 4; ++ks) {
                const bf16x8 a = *(const bf16x8*)(xa + ks * 32);
#pragma unroll
                for (int cf = 0; cf < 4; ++cf) {
                    const bf16x8 b = *(const bf16x8*)(wx_base + (ks * 4 + cf) * 512 + lane * 8);
                    acc[cf] = __builtin_amdgcn_mfma_f32_16x16x32_bf16(a, b, acc[cf], 0, 0, 0);
                }
            }
        }
    }
}

extern "C" void kernel_launch(void* const* d_in, const int* in_sizes, int n_in,
                              void* d_out, int out_size, void* d_ws, size_t ws_size,
                              hipStream_t stream) {
    const float* x  = (const float*)d_in[0];
    const float* Wf = (const float*)d_in[1];
    const float* Wi = (const float*)d_in[2];
    const float* Wo = (const float*)d_in[3];
    const float* Wu = (const float*)d_in[4];
    const float* bf = (const float*)d_in[5];
    const float* bi = (const float*)d_in[6];
    const float* bo = (const float*)d_in[7];
    const float* bu = (const float*)d_in[8];
    float* out = (float*)d_out;

    char* ws = (char*)d_ws;
    bf16_t*   xb     = (bf16_t*)(ws + XB_OFF);
    bf16_t*   wxt    = (bf16_t*)(ws + WXT_OFF);
    uint32_t* flags  = (uint32_t*)(ws + FLAGS_OFF);
    bf16_t*   hslots = (bf16_t*)(ws + HS_OFF);

    // zero flags + both h slots (every launch/replay)
    (void)hipMemsetAsync(ws + FLAGS_OFF, 0, MEMSET_BYTES, stream);

    // convert x -> bf16; transpose x-weights into frag order
    xconv_kernel<<<16384, 256, 0, stream>>>(x, xb);
    wxt_prep<<<1024, 256, 0, stream>>>(Wf, Wi, Wo, Wu, wxt);

    (void)hipFuncSetAttribute((const void*)lstm_main,
                              hipFuncAttributeMaxDynamicSharedMemorySize, LDS_BYTES);

    lstm_main<<<NWG, 256, LDS_BYTES, stream>>>(Wf, Wi, Wo, Wu, bf, bi, bo, bu,
                                               xb, wxt, hslots, flags, out);
}